// Round 18
// baseline (232.081 us; speedup 1.0000x reference)
//
#include <hip/hip_runtime.h>
#include <math.h>

#define NROWS 2048
#define DDIM 32

typedef __attribute__((ext_vector_type(8))) short short8;  // 8 bf16
typedef __attribute__((ext_vector_type(4))) float f32x4;

__device__ __forceinline__ unsigned packbf(float a, float b) {
  // bf16(a) in low 16, bf16(b) in high 16 (truncation; lo-plane captures rest)
  return (__float_as_uint(a) >> 16) | (__float_as_uint(b) & 0xffff0000u);
}

// ---------------------------------------------------------------------------
// Single fused kernel. 128x128 tile per 512-thread block (8 waves, 2/SIMD).
// r14 champion structure, with the redundant per-block stats stream woven
// into the FULLY-UNROLLED 16-phase quantum loop (2-deep compile-time
// double-buffer; <=8 global loads in flight). Quantum phases cover the L2
// latency of the stats loads; per-thread accumulation order is identical to
// r14 (bit-identical output).
// Order: tile loads -> cs staging -> barrier -> quantum+stats (fused) ->
//   stats reduce -> bf16 hi/lo staging -> MFMA classical -> combine -> store.
// classical = exp(2*dot - nx - ny); quantum term = 0.5 + hcx*cy + hsx*sy.
// ---------------------------------------------------------------------------
__global__ __launch_bounds__(512, 2) void HybridKernel_fused(
    const float* __restrict__ x, const float* __restrict__ y,
    float* __restrict__ out) {
  __shared__ float4 sCS[2][16 * 128];   // 64 KB swizzled cos/sin pairs
  __shared__ uint4 sXB[2][2][128 * 5];  // 40 KB bf16 [side][hi/lo], 80B/row
  __shared__ f32x4 sRed[2][64][8];      // 16 KB stats partials (sum)
  __shared__ f32x4 sRedQ[2][64][8];     // 16 KB stats partials (sumsq)
  __shared__ float sNrm[2][128];
  __shared__ float sMu[2][32];
  __shared__ float sInv[2][32];

  const int t = threadIdx.x;
  const int i0 = blockIdx.y * 128;
  const int j0 = blockIdx.x * 128;

  // --- 1. hoist tile global loads ---
  float4 gx[2], gy[2];
#pragma unroll
  for (int rep = 0; rep < 2; ++rep) {
    const int u = t + 512 * rep;
    const int row = u >> 3;
    const int q = u & 7;
    gx[rep] = *reinterpret_cast<const float4*>(&x[(i0 + row) * DDIM + q * 4]);
    gy[rep] = *reinterpret_cast<const float4*>(&y[(j0 + row) * DDIM + q * 4]);
  }

  // --- 2. cs staging (raw values only) ---
#pragma unroll
  for (int rep = 0; rep < 2; ++rep) {
    const int u = t + 512 * rep;
    const int row = u >> 3;
    const int q = u & 7;
#pragma unroll
    for (int side = 0; side < 2; ++side) {
      const float4 g = side ? gy[rep] : gx[rep];
      const float sc = side ? 1.0f : 0.5f;
      const float gv[4] = {g.x, g.y, g.z, g.w};
      float hc[4], hs[4];
#pragma unroll
      for (int k = 0; k < 4; ++k) {
        float sn, cs;
        __sincosf(gv[k], &sn, &cs);
        hc[k] = sc * cs;
        hs[k] = sc * sn;
      }
      const int dp0 = 2 * q, dp1 = 2 * q + 1;
      sCS[side][dp0 * 128 + (row ^ (dp0 & 7))] =
          make_float4(hc[0], hs[0], hc[1], hs[1]);
      sCS[side][dp1 * 128 + (row ^ (dp1 & 7))] =
          make_float4(hc[2], hs[2], hc[3], hs[3]);
    }
  }
  __syncthreads();

  // --- wave/lane geometry (MFMA C/D layout) ---
  const int w = t >> 6;
  const int l = t & 63;
  const int l4 = l >> 4;  // 0..3
  const int ln = l & 15;
  const int R0 = (w >> 1) * 32;  // wave row base
  const int C0 = (w & 1) * 64;   // wave col base

  int r_idx[8], c_idx[4];
#pragma unroll
  for (int ri = 0; ri < 8; ++ri)
    r_idx[ri] = R0 + 16 * (ri >> 2) + 4 * l4 + (ri & 3);
#pragma unroll
  for (int tc = 0; tc < 4; ++tc) c_idx[tc] = C0 + 16 * tc + ln;

  // --- 3. quantum (16 fully-unrolled phases) + stats stream (pipelined) ---
  const int cq = t & 7;
  const int rg = t >> 3;  // 0..63
  const f32x4* px = reinterpret_cast<const f32x4*>(x) + rg * 8 + cq;
  const f32x4* py = reinterpret_cast<const f32x4*>(y) + rg * 8 + cq;
  f32x4 sxA = {0.f, 0.f, 0.f, 0.f}, qxA = {0.f, 0.f, 0.f, 0.f};
  f32x4 syA = {0.f, 0.f, 0.f, 0.f}, qyA = {0.f, 0.f, 0.f, 0.f};
  f32x4 vxb[2][2], vyb[2][2];  // 2-deep chunk double-buffer (parity-indexed)

  // prologue: issue chunk 0 (rows rg+0, rg+64)
  vxb[0][0] = px[0];
  vxb[0][1] = px[512];
  vyb[0][0] = py[0];
  vyb[0][1] = py[512];

  const float4* sCS0 = &sCS[0][0];
  const float4* sCS1 = &sCS[1][0];
  float qp[8][4];
#pragma unroll
  for (int ri = 0; ri < 8; ++ri)
#pragma unroll
    for (int tc = 0; tc < 4; ++tc) qp[ri][tc] = 1.f;

#pragma unroll
  for (int dp = 0; dp < 16; ++dp) {
    // consume chunk dp-1 (counted vmcnt wait; chunk dp stays in flight)
    if (dp >= 1) {
      const int b = (dp - 1) & 1;
#pragma unroll
      for (int h = 0; h < 2; ++h) {
        const f32x4 vx = vxb[b][h];
        const f32x4 vy = vyb[b][h];
        sxA += vx;
        qxA = __builtin_elementwise_fma(vx, vx, qxA);
        syA += vy;
        qyA = __builtin_elementwise_fma(vy, vy, qyA);
      }
    }
    // issue chunk dp+1 (rows rg + 64*(2(dp+1)), rg + 64*(2(dp+1)+1))
    if (dp + 1 < 16) {
      const int b = (dp + 1) & 1;
      vxb[b][0] = px[(size_t)(2 * (dp + 1)) * 512];
      vxb[b][1] = px[(size_t)(2 * (dp + 1) + 1) * 512];
      vyb[b][0] = py[(size_t)(2 * (dp + 1)) * 512];
      vyb[b][1] = py[(size_t)(2 * (dp + 1) + 1) * 512];
    }
    // quantum phase dp (identical to r14 champion)
    const int sw = dp & 7;
    const int base = dp * 128;
    float4 FX[8], FY[4];
#pragma unroll
    for (int ri = 0; ri < 8; ++ri) FX[ri] = sCS0[base + (r_idx[ri] ^ sw)];
#pragma unroll
    for (int tc = 0; tc < 4; ++tc) FY[tc] = sCS1[base + (c_idx[tc] ^ sw)];
#pragma unroll
    for (int ri = 0; ri < 8; ++ri)
#pragma unroll
      for (int tc = 0; tc < 4; ++tc) {
        const float t0 =
            fmaf(FX[ri].x, FY[tc].x, fmaf(FX[ri].y, FY[tc].y, 0.5f));
        const float t1 =
            fmaf(FX[ri].z, FY[tc].z, fmaf(FX[ri].w, FY[tc].w, 0.5f));
        qp[ri][tc] *= t0 * t1;
      }
  }
  // epilogue: consume chunk 15
  {
#pragma unroll
    for (int h = 0; h < 2; ++h) {
      const f32x4 vx = vxb[1][h];
      const f32x4 vy = vyb[1][h];
      sxA += vx;
      qxA = __builtin_elementwise_fma(vx, vx, qxA);
      syA += vy;
      qyA = __builtin_elementwise_fma(vy, vy, qyA);
    }
  }

  // --- 4. stats reduce ---
  sRed[0][rg][cq] = sxA;
  sRedQ[0][rg][cq] = qxA;
  sRed[1][rg][cq] = syA;
  sRedQ[1][rg][cq] = qyA;
  __syncthreads();
  if (t < 128) {
    const int a = t >> 6;
    const int g8 = (t >> 3) & 7;
    const int cq2 = t & 7;
    f32x4 S = {0.f, 0.f, 0.f, 0.f}, Q = {0.f, 0.f, 0.f, 0.f};
#pragma unroll
    for (int k = 0; k < 8; ++k) {
      S += sRed[a][g8 * 8 + k][cq2];
      Q += sRedQ[a][g8 * 8 + k][cq2];
    }
    sRed[a][g8][cq2] = S;
    sRedQ[a][g8][cq2] = Q;
  }
  __syncthreads();
  if (t < 16) {  // t = a*8 + cq
    const int a = t >> 3;
    const int cq2 = t & 7;
    f32x4 S = {0.f, 0.f, 0.f, 0.f}, Q = {0.f, 0.f, 0.f, 0.f};
#pragma unroll
    for (int k = 0; k < 8; ++k) {
      S += sRed[a][k][cq2];
      Q += sRedQ[a][k][cq2];
    }
    const float n = (float)NROWS;
#pragma unroll
    for (int k = 0; k < 4; ++k) {
      const float mean = S[k] / n;
      const float var = fmaxf((Q[k] - S[k] * mean) / (n - 1.f), 0.f);
      sMu[a][cq2 * 4 + k] = mean;
      sInv[a][cq2 * 4 + k] = 1.f / (sqrtf(var) + 1e-8f);
    }
  }
  __syncthreads();

  // --- 5. bf16 hi/lo staging + row norms ---
#pragma unroll
  for (int rep = 0; rep < 2; ++rep) {
    const int u = t + 512 * rep;
    const int row = u >> 3;
    const int q = u & 7;
#pragma unroll
    for (int side = 0; side < 2; ++side) {
      const float4 g = side ? gy[rep] : gx[rep];
      const float gv[4] = {g.x, g.y, g.z, g.w};
      float xn[4];
      float nrm = 0.f;
#pragma unroll
      for (int k = 0; k < 4; ++k) {
        const int d = q * 4 + k;
        xn[k] = (gv[k] - sMu[side][d]) * sInv[side][d];
        nrm = fmaf(xn[k], xn[k], nrm);
      }
      float hif[4], lof[4];
#pragma unroll
      for (int k = 0; k < 4; ++k) {
        hif[k] = __uint_as_float(__float_as_uint(xn[k]) & 0xffff0000u);
        lof[k] = xn[k] - hif[k];
      }
      char* bh = (char*)&sXB[side][0][0] + row * 80 + q * 8;
      char* bl = (char*)&sXB[side][1][0] + row * 80 + q * 8;
      *reinterpret_cast<uint2*>(bh) =
          make_uint2(packbf(hif[0], hif[1]), packbf(hif[2], hif[3]));
      *reinterpret_cast<uint2*>(bl) =
          make_uint2(packbf(lof[0], lof[1]), packbf(lof[2], lof[3]));
      nrm += __shfl_xor(nrm, 1);
      nrm += __shfl_xor(nrm, 2);
      nrm += __shfl_xor(nrm, 4);
      if ((t & 7) == 0) sNrm[side][row] = nrm;
    }
  }
  __syncthreads();

  // --- 6. classical via MFMA: 2x4 tiles, hi/lo 3-pass ---
  short8 Ah[2], Al[2], Bh[4], Bl[4];
  {
    const char* bxh = (const char*)&sXB[0][0][0];
    const char* bxl = (const char*)&sXB[0][1][0];
    const char* byh = (const char*)&sXB[1][0][0];
    const char* byl = (const char*)&sXB[1][1][0];
#pragma unroll
    for (int tr = 0; tr < 2; ++tr) {
      const int off = (R0 + 16 * tr + ln) * 80 + l4 * 16;
      Ah[tr] = *reinterpret_cast<const short8*>(bxh + off);
      Al[tr] = *reinterpret_cast<const short8*>(bxl + off);
    }
#pragma unroll
    for (int tc = 0; tc < 4; ++tc) {
      const int off = (C0 + 16 * tc + ln) * 80 + l4 * 16;
      Bh[tc] = *reinterpret_cast<const short8*>(byh + off);
      Bl[tc] = *reinterpret_cast<const short8*>(byl + off);
    }
  }
  f32x4 dotacc[2][4];
#pragma unroll
  for (int tr = 0; tr < 2; ++tr)
#pragma unroll
    for (int tc = 0; tc < 4; ++tc) {
      f32x4 a = {0.f, 0.f, 0.f, 0.f};
      a = __builtin_amdgcn_mfma_f32_16x16x32_bf16(Ah[tr], Bl[tc], a, 0, 0, 0);
      a = __builtin_amdgcn_mfma_f32_16x16x32_bf16(Al[tr], Bh[tc], a, 0, 0, 0);
      a = __builtin_amdgcn_mfma_f32_16x16x32_bf16(Ah[tr], Bh[tc], a, 0, 0, 0);
      dotacc[tr][tc] = a;
    }

  // --- 7. classical epilogue + combine + store ---
#pragma unroll
  for (int tr = 0; tr < 2; ++tr) {
#pragma unroll
    for (int mm = 0; mm < 4; ++mm) {
      const int ri = tr * 4 + mm;
      const float nx = sNrm[0][r_idx[ri]];
      float* o = out + (size_t)(i0 + r_idx[ri]) * NROWS + j0;
#pragma unroll
      for (int tc = 0; tc < 4; ++tc) {
        const float ny = sNrm[1][c_idx[tc]];
        const float cl = __expf(2.f * dotacc[tr][tc][mm] - nx - ny);
        o[c_idx[tc]] = 0.5f * (cl + qp[ri][tc]);
      }
    }
  }
}

extern "C" void kernel_launch(void* const* d_in, const int* in_sizes, int n_in,
                              void* d_out, int out_size, void* d_ws,
                              size_t ws_size, hipStream_t stream) {
  const float* x = (const float*)d_in[0];
  const float* y = (const float*)d_in[1];
  float* out = (float*)d_out;

  dim3 grid(NROWS / 128, NROWS / 128);
  HybridKernel_fused<<<grid, 512, 0, stream>>>(x, y, out);
}

// Round 19
// 27.483 us; speedup vs baseline: 8.4447x; 8.4447x over previous
//
#include <hip/hip_runtime.h>
#include <hip/hip_fp16.h>
#include <math.h>

#define NROWS 2048
#define DDIM 32

typedef __attribute__((ext_vector_type(8))) short short8;  // 8 bf16
typedef __attribute__((ext_vector_type(4))) float f32x4;
typedef _Float16 h2 __attribute__((ext_vector_type(2)));

union H8 {
  h2 p[4];
  _Float16 h[8];
  uint4 u;
};

__device__ __forceinline__ unsigned packbf(float a, float b) {
  // bf16(a) in low 16, bf16(b) in high 16 (truncation; lo-plane captures rest)
  return (__float_as_uint(a) >> 16) | (__float_as_uint(b) & 0xffff0000u);
}

// ---------------------------------------------------------------------------
// Single fused kernel. 128x128 tile per 512-thread block (8 waves, 2/SIMD).
// r14 champion structure, but cos/sin stored as fp16 quads (4 d's per b128)
// and the quantum term computed with v_dot2_f32_f16 (__builtin_amdgcn_fdot2):
//   term_d = hcx*hcy + hsx*hsy + 0.5  ==  fdot2(fx.p[d], fy.p[d], 0.5)
// -> 8 quantum phases of 12 ds_read_b128 (was 16), no fp16->f32 conversion
// ops (r17's mistake). fp16 quantization error ~6e-5 (measured r17), well
// under the 3.7e-4 threshold. Classical path exact as before.
//   sCSh[side][q*128 + (row ^ q)] : uint4 = 8 fp16 (hc0,hs0,...,hc3,hs3),
//   q = d-quad 0..7. x side folds ALPHA=0.5 into hc/hs.
// Order: tile loads -> cs staging -> stats stream -> reduce -> bf16 hi/lo
//   staging -> MFMA classical -> quantum (fdot2) -> combine -> store.
// classical = exp(2*dot - nx - ny); quantum term = 0.5 + hcx*cy + hsx*sy.
// ---------------------------------------------------------------------------
__global__ __launch_bounds__(512, 2) void HybridKernel_fused(
    const float* __restrict__ x, const float* __restrict__ y,
    float* __restrict__ out) {
  __shared__ uint4 sCSh[2][8 * 128];    // 32 KB fp16 cos/sin quads
  __shared__ uint4 sXB[2][2][128 * 5];  // 40 KB bf16 [side][hi/lo], 80B/row
  __shared__ f32x4 sRed[2][64][8];      // 16 KB stats partials (sum)
  __shared__ f32x4 sRedQ[2][64][8];     // 16 KB stats partials (sumsq)
  __shared__ float sNrm[2][128];
  __shared__ float sMu[2][32];
  __shared__ float sInv[2][32];

  const int t = threadIdx.x;
  const int i0 = blockIdx.y * 128;
  const int j0 = blockIdx.x * 128;

  // --- 1. hoist tile global loads ---
  float4 gx[2], gy[2];
#pragma unroll
  for (int rep = 0; rep < 2; ++rep) {
    const int u = t + 512 * rep;
    const int row = u >> 3;
    const int q = u & 7;
    gx[rep] = *reinterpret_cast<const float4*>(&x[(i0 + row) * DDIM + q * 4]);
    gy[rep] = *reinterpret_cast<const float4*>(&y[(j0 + row) * DDIM + q * 4]);
  }

  // --- 2. cs staging (fp16 pack, 4 d's per slot) ---
#pragma unroll
  for (int rep = 0; rep < 2; ++rep) {
    const int u = t + 512 * rep;
    const int row = u >> 3;
    const int q = u & 7;
#pragma unroll
    for (int side = 0; side < 2; ++side) {
      const float4 g = side ? gy[rep] : gx[rep];
      const float sc = side ? 1.0f : 0.5f;
      const float gv[4] = {g.x, g.y, g.z, g.w};
      H8 pk;
#pragma unroll
      for (int k = 0; k < 4; ++k) {
        float sn, cs;
        __sincosf(gv[k], &sn, &cs);
        pk.h[2 * k] = (_Float16)(sc * cs);
        pk.h[2 * k + 1] = (_Float16)(sc * sn);
      }
      sCSh[side][q * 128 + (row ^ q)] = pk.u;
    }
  }

  // --- 3. stats streaming ---
  {
    const int cq = t & 7;
    const int rg = t >> 3;  // 0..63
    const f32x4* px = reinterpret_cast<const f32x4*>(x) + rg * 8 + cq;
    const f32x4* py = reinterpret_cast<const f32x4*>(y) + rg * 8 + cq;
    f32x4 sx = {0.f, 0.f, 0.f, 0.f}, qx = {0.f, 0.f, 0.f, 0.f};
    f32x4 sy = {0.f, 0.f, 0.f, 0.f}, qy = {0.f, 0.f, 0.f, 0.f};
#pragma unroll 4
    for (int i = 0; i < NROWS / 64; ++i) {  // 32 iters
      const f32x4 vx = px[(size_t)i * 64 * 8];
      const f32x4 vy = py[(size_t)i * 64 * 8];
      sx += vx;
      qx = __builtin_elementwise_fma(vx, vx, qx);
      sy += vy;
      qy = __builtin_elementwise_fma(vy, vy, qy);
    }
    sRed[0][rg][cq] = sx;
    sRedQ[0][rg][cq] = qx;
    sRed[1][rg][cq] = sy;
    sRedQ[1][rg][cq] = qy;
  }
  __syncthreads();
  if (t < 128) {
    const int a = t >> 6;
    const int g8 = (t >> 3) & 7;
    const int cq2 = t & 7;
    f32x4 S = {0.f, 0.f, 0.f, 0.f}, Q = {0.f, 0.f, 0.f, 0.f};
#pragma unroll
    for (int k = 0; k < 8; ++k) {
      S += sRed[a][g8 * 8 + k][cq2];
      Q += sRedQ[a][g8 * 8 + k][cq2];
    }
    sRed[a][g8][cq2] = S;
    sRedQ[a][g8][cq2] = Q;
  }
  __syncthreads();
  if (t < 16) {  // t = a*8 + cq
    const int a = t >> 3;
    const int cq2 = t & 7;
    f32x4 S = {0.f, 0.f, 0.f, 0.f}, Q = {0.f, 0.f, 0.f, 0.f};
#pragma unroll
    for (int k = 0; k < 8; ++k) {
      S += sRed[a][k][cq2];
      Q += sRedQ[a][k][cq2];
    }
    const float n = (float)NROWS;
#pragma unroll
    for (int k = 0; k < 4; ++k) {
      const float mean = S[k] / n;
      const float var = fmaxf((Q[k] - S[k] * mean) / (n - 1.f), 0.f);
      sMu[a][cq2 * 4 + k] = mean;
      sInv[a][cq2 * 4 + k] = 1.f / (sqrtf(var) + 1e-8f);
    }
  }
  __syncthreads();

  // --- 4. bf16 hi/lo staging + row norms ---
#pragma unroll
  for (int rep = 0; rep < 2; ++rep) {
    const int u = t + 512 * rep;
    const int row = u >> 3;
    const int q = u & 7;
#pragma unroll
    for (int side = 0; side < 2; ++side) {
      const float4 g = side ? gy[rep] : gx[rep];
      const float gv[4] = {g.x, g.y, g.z, g.w};
      float xn[4];
      float nrm = 0.f;
#pragma unroll
      for (int k = 0; k < 4; ++k) {
        const int d = q * 4 + k;
        xn[k] = (gv[k] - sMu[side][d]) * sInv[side][d];
        nrm = fmaf(xn[k], xn[k], nrm);
      }
      float hif[4], lof[4];
#pragma unroll
      for (int k = 0; k < 4; ++k) {
        hif[k] = __uint_as_float(__float_as_uint(xn[k]) & 0xffff0000u);
        lof[k] = xn[k] - hif[k];
      }
      char* bh = (char*)&sXB[side][0][0] + row * 80 + q * 8;
      char* bl = (char*)&sXB[side][1][0] + row * 80 + q * 8;
      *reinterpret_cast<uint2*>(bh) =
          make_uint2(packbf(hif[0], hif[1]), packbf(hif[2], hif[3]));
      *reinterpret_cast<uint2*>(bl) =
          make_uint2(packbf(lof[0], lof[1]), packbf(lof[2], lof[3]));
      nrm += __shfl_xor(nrm, 1);
      nrm += __shfl_xor(nrm, 2);
      nrm += __shfl_xor(nrm, 4);
      if ((t & 7) == 0) sNrm[side][row] = nrm;
    }
  }
  __syncthreads();

  // --- wave/lane geometry (MFMA C/D layout) ---
  const int w = t >> 6;
  const int l = t & 63;
  const int l4 = l >> 4;  // 0..3
  const int ln = l & 15;
  const int R0 = (w >> 1) * 32;  // wave row base
  const int C0 = (w & 1) * 64;   // wave col base

  int r_idx[8], c_idx[4];
#pragma unroll
  for (int ri = 0; ri < 8; ++ri)
    r_idx[ri] = R0 + 16 * (ri >> 2) + 4 * l4 + (ri & 3);
#pragma unroll
  for (int tc = 0; tc < 4; ++tc) c_idx[tc] = C0 + 16 * tc + ln;

  // --- 5. classical via MFMA: 2x4 tiles, hi/lo 3-pass ---
  short8 Ah[2], Al[2], Bh[4], Bl[4];
  {
    const char* bxh = (const char*)&sXB[0][0][0];
    const char* bxl = (const char*)&sXB[0][1][0];
    const char* byh = (const char*)&sXB[1][0][0];
    const char* byl = (const char*)&sXB[1][1][0];
#pragma unroll
    for (int tr = 0; tr < 2; ++tr) {
      const int off = (R0 + 16 * tr + ln) * 80 + l4 * 16;
      Ah[tr] = *reinterpret_cast<const short8*>(bxh + off);
      Al[tr] = *reinterpret_cast<const short8*>(bxl + off);
    }
#pragma unroll
    for (int tc = 0; tc < 4; ++tc) {
      const int off = (C0 + 16 * tc + ln) * 80 + l4 * 16;
      Bh[tc] = *reinterpret_cast<const short8*>(byh + off);
      Bl[tc] = *reinterpret_cast<const short8*>(byl + off);
    }
  }
  f32x4 dotacc[2][4];
#pragma unroll
  for (int tr = 0; tr < 2; ++tr)
#pragma unroll
    for (int tc = 0; tc < 4; ++tc) {
      f32x4 a = {0.f, 0.f, 0.f, 0.f};
      a = __builtin_amdgcn_mfma_f32_16x16x32_bf16(Ah[tr], Bl[tc], a, 0, 0, 0);
      a = __builtin_amdgcn_mfma_f32_16x16x32_bf16(Al[tr], Bh[tc], a, 0, 0, 0);
      a = __builtin_amdgcn_mfma_f32_16x16x32_bf16(Ah[tr], Bh[tc], a, 0, 0, 0);
      dotacc[tr][tc] = a;
    }

  // --- 6. quantum: 8 phases, fp16 pairs via v_dot2_f32_f16 (no cvt ops) ---
  const uint4* sCS0 = &sCSh[0][0];
  const uint4* sCS1 = &sCSh[1][0];
  float qp[8][4];
#pragma unroll
  for (int ri = 0; ri < 8; ++ri)
#pragma unroll
    for (int tc = 0; tc < 4; ++tc) qp[ri][tc] = 1.f;

#pragma unroll
  for (int q = 0; q < 8; ++q) {
    const int base = q * 128;
    H8 fy[4];
#pragma unroll
    for (int tc = 0; tc < 4; ++tc) fy[tc].u = sCS1[base + (c_idx[tc] ^ q)];
#pragma unroll
    for (int ri = 0; ri < 8; ++ri) {
      H8 fx;
      fx.u = sCS0[base + (r_idx[ri] ^ q)];
#pragma unroll
      for (int tc = 0; tc < 4; ++tc) {
        const float t0 = __builtin_amdgcn_fdot2(fx.p[0], fy[tc].p[0], 0.5f, false);
        const float t1 = __builtin_amdgcn_fdot2(fx.p[1], fy[tc].p[1], 0.5f, false);
        const float t2 = __builtin_amdgcn_fdot2(fx.p[2], fy[tc].p[2], 0.5f, false);
        const float t3 = __builtin_amdgcn_fdot2(fx.p[3], fy[tc].p[3], 0.5f, false);
        qp[ri][tc] *= (t0 * t1) * (t2 * t3);
      }
    }
  }

  // --- 7. classical epilogue + combine + store ---
#pragma unroll
  for (int tr = 0; tr < 2; ++tr) {
#pragma unroll
    for (int mm = 0; mm < 4; ++mm) {
      const int ri = tr * 4 + mm;
      const float nx = sNrm[0][r_idx[ri]];
      float* o = out + (size_t)(i0 + r_idx[ri]) * NROWS + j0;
#pragma unroll
      for (int tc = 0; tc < 4; ++tc) {
        const float ny = sNrm[1][c_idx[tc]];
        const float cl = __expf(2.f * dotacc[tr][tc][mm] - nx - ny);
        o[c_idx[tc]] = 0.5f * (cl + qp[ri][tc]);
      }
    }
  }
}

extern "C" void kernel_launch(void* const* d_in, const int* in_sizes, int n_in,
                              void* d_out, int out_size, void* d_ws,
                              size_t ws_size, hipStream_t stream) {
  const float* x = (const float*)d_in[0];
  const float* y = (const float*)d_in[1];
  float* out = (float*)d_out;

  dim3 grid(NROWS / 128, NROWS / 128);
  HybridKernel_fused<<<grid, 512, 0, stream>>>(x, y, out);
}